// Round 2
// baseline (27.403 us; speedup 1.0000x reference)
//
#include <hip/hip_runtime.h>

#define KK 784      // 28*28 pixels per image
#define NE 5        // experts

__global__ __launch_bounds__(256, 6) void moe_conv_fused_kernel(
    const float* __restrict__ x,        // [B, 784]
    const int*   __restrict__ cat,      // [B]
    const float* __restrict__ conv_w,   // [5, 784]
    const float* __restrict__ conv_b,   // [5]
    const float* __restrict__ fc1_w,    // [1, 5] -> 5 floats
    const float* __restrict__ fc1_b,    // [1]
    float*       __restrict__ out,      // [B]
    int B)
{
    __shared__ float w_lds[NE * KK];    // 15680 B
    __shared__ float cb_lds[NE];
    __shared__ float fw_lds[NE];

    // cooperative stage of all 5 expert weight rows (float4-vectorized)
    {
        const float4* src = reinterpret_cast<const float4*>(conv_w);
        float4* dst = reinterpret_cast<float4*>(w_lds);
        for (int i = threadIdx.x; i < (NE * KK) / 4; i += blockDim.x)
            dst[i] = src[i];
        if (threadIdx.x < NE) {
            cb_lds[threadIdx.x] = conv_b[threadIdx.x];
            fw_lds[threadIdx.x] = fc1_w[threadIdx.x];
        }
    }
    __syncthreads();

    const float fb = fc1_b[0];
    const int lane   = threadIdx.x & 63;
    const int wave   = (blockIdx.x * blockDim.x + threadIdx.x) >> 6;
    const int nwaves = (gridDim.x * blockDim.x) >> 6;

    // each wave iteration: TWO adjacent samples -> 6.2KB contiguous read,
    // 6-8 global loads in flight, two independent reduce chains overlap
    for (int s0 = 2 * wave; s0 < B; s0 += 2 * nwaves) {
        const int s1 = s0 + 1;
        const bool have2 = (s1 < B);

        int e0, e1;
        if (have2) {
            const int2 cc = *reinterpret_cast<const int2*>(cat + s0); // s0 even -> 8B aligned
            e0 = cc.x; e1 = cc.y;
        } else {
            e0 = cat[s0]; e1 = e0;
        }

        const float4* xv0 = reinterpret_cast<const float4*>(x + (size_t)s0 * KK);
        const float4* xv1 = have2 ? (xv0 + (KK / 4)) : xv0;   // alias to avoid OOB
        const float4* wv0 = reinterpret_cast<const float4*>(w_lds + e0 * KK);
        const float4* wv1 = reinterpret_cast<const float4*>(w_lds + e1 * KK);

        // issue all global loads up front (MLP)
        float4 a0 = xv0[lane];
        float4 a1 = xv0[lane + 64];
        float4 a2 = xv0[lane + 128];
        float4 c0 = xv1[lane];
        float4 c1 = xv1[lane + 64];
        float4 c2 = xv1[lane + 128];
        float4 a3, c3;
        if (lane < 4) {
            a3 = xv0[192 + lane];
            c3 = xv1[192 + lane];
        }

        // LDS weight fragments
        float4 b0 = wv0[lane];
        float4 b1 = wv0[lane + 64];
        float4 b2 = wv0[lane + 128];
        float4 d0 = wv1[lane];
        float4 d1 = wv1[lane + 64];
        float4 d2 = wv1[lane + 128];

        float acc0, acc1;
        acc0  = a0.x * b0.x + a0.y * b0.y + a0.z * b0.z + a0.w * b0.w;
        acc0 += a1.x * b1.x + a1.y * b1.y + a1.z * b1.z + a1.w * b1.w;
        acc0 += a2.x * b2.x + a2.y * b2.y + a2.z * b2.z + a2.w * b2.w;
        acc1  = c0.x * d0.x + c0.y * d0.y + c0.z * d0.z + c0.w * d0.w;
        acc1 += c1.x * d1.x + c1.y * d1.y + c1.z * d1.z + c1.w * d1.w;
        acc1 += c2.x * d2.x + c2.y * d2.y + c2.z * d2.z + c2.w * d2.w;
        if (lane < 4) {
            float4 b3 = wv0[192 + lane];
            float4 d3 = wv1[192 + lane];
            acc0 += a3.x * b3.x + a3.y * b3.y + a3.z * b3.z + a3.w * b3.w;
            acc1 += c3.x * d3.x + c3.y * d3.y + c3.z * d3.z + c3.w * d3.w;
        }

        // two independent wave-wide reduce chains, interleaved
        #pragma unroll
        for (int off = 32; off > 0; off >>= 1) {
            acc0 += __shfl_down(acc0, off, 64);
            acc1 += __shfl_down(acc1, off, 64);
        }

        if (lane == 0) {
            float o0 = (acc0 + cb_lds[e0]) * fw_lds[e0] + fb;
            o0 = o0 > 0.0f ? o0 : 0.0f;
            if (have2) {
                float o1 = (acc1 + cb_lds[e1]) * fw_lds[e1] + fb;
                o1 = o1 > 0.0f ? o1 : 0.0f;
                float2 o; o.x = o0; o.y = o1;
                *reinterpret_cast<float2*>(out + s0) = o;  // s0 even -> aligned
            } else {
                out[s0] = o0;
            }
        }
    }
}

extern "C" void kernel_launch(void* const* d_in, const int* in_sizes, int n_in,
                              void* d_out, int out_size, void* d_ws, size_t ws_size,
                              hipStream_t stream) {
    const float* x      = (const float*)d_in[0];
    const int*   cat    = (const int*)d_in[1];
    const float* conv_w = (const float*)d_in[2];
    const float* conv_b = (const float*)d_in[3];
    const float* fc1_w  = (const float*)d_in[4];
    const float* fc1_b  = (const float*)d_in[5];
    float* out = (float*)d_out;

    const int B = in_sizes[1];          // category_indices element count
    (void)d_ws; (void)ws_size; (void)n_in; (void)out_size;

    const int block = 256;              // 4 waves/block
    const int pairs = (B + 1) / 2;      // one pair per wave iteration
    int grid = 2048;                    // 256 CU x 8 blocks queued
    const int blocks_needed = (pairs + 3) / 4;   // 4 waves per block
    if (grid > blocks_needed) grid = blocks_needed;

    moe_conv_fused_kernel<<<grid, block, 0, stream>>>(
        x, cat, conv_w, conv_b, fc1_w, fc1_b, out, B);
}

// Round 3
// 20.925 us; speedup vs baseline: 1.3096x; 1.3096x over previous
//
#include <hip/hip_runtime.h>

#define KK 784      // 28*28 pixels per image
#define NE 5        // experts

__device__ __forceinline__ float dot4(float4 a, float4 b) {
    return a.x * b.x + a.y * b.y + a.z * b.z + a.w * b.w;
}

// One wave = 4 adjacent samples, one 16-lane group per sample, single pass.
// No LDS, no loop: weights (15.7 KB) live in L1/L2; 12-13 independent
// float4 loads per lane issue back-to-back; 4-step shuffle reduce shared
// by all 4 samples at once.
__global__ __launch_bounds__(256, 4) void moe_conv_fused_kernel(
    const float* __restrict__ x,        // [B, 784]
    const int*   __restrict__ cat,      // [B]
    const float* __restrict__ conv_w,   // [5, 784]
    const float* __restrict__ conv_b,   // [5]
    const float* __restrict__ fc1_w,    // [1, 5] -> 5 floats
    const float* __restrict__ fc1_b,    // [1]
    float*       __restrict__ out,      // [B]
    int B)
{
    const int tid  = blockIdx.x * blockDim.x + threadIdx.x;
    const int wid  = tid >> 6;                 // global wave id
    const int lane = threadIdx.x & 63;
    const int grp  = lane >> 4;                // 0..3 : sample within wave
    const int sub  = lane & 15;                // lane within 16-lane group
    const int s    = wid * 4 + grp;            // sample id (one shot, no loop)
    if (s >= B) return;

    const int e = cat[s];                      // uniform per 16-lane group
    const float4* __restrict__ xv =
        reinterpret_cast<const float4*>(x) + (size_t)s * (KK / 4);
    const float4* __restrict__ wv =
        reinterpret_cast<const float4*>(conv_w) + (size_t)e * (KK / 4);

    // 196 float4 per sample over 16 lanes: 12 each + lanes 0..3 take #192+sub
    float4 xa[12];
    #pragma unroll
    for (int i = 0; i < 12; ++i)
        xa[i] = xv[sub + 16 * i];              // all independent, issue early

    const bool extra = (sub < 4);
    float4 xt;
    if (extra) xt = xv[192 + sub];

    // stream weights (L1-hot) in chunks; 4 accumulators break the FMA chain
    float a0 = 0.f, a1 = 0.f, a2 = 0.f, a3 = 0.f;
    #pragma unroll
    for (int i = 0; i < 12; i += 4) {
        float4 w0 = wv[sub + 16 * (i + 0)];
        float4 w1 = wv[sub + 16 * (i + 1)];
        float4 w2 = wv[sub + 16 * (i + 2)];
        float4 w3 = wv[sub + 16 * (i + 3)];
        a0 += dot4(xa[i + 0], w0);
        a1 += dot4(xa[i + 1], w1);
        a2 += dot4(xa[i + 2], w2);
        a3 += dot4(xa[i + 3], w3);
    }
    if (extra) {
        float4 wt = wv[192 + sub];
        a0 += dot4(xt, wt);
    }
    float acc = (a0 + a1) + (a2 + a3);

    // reduce within each 16-lane group (4 samples reduced simultaneously)
    #pragma unroll
    for (int off = 8; off > 0; off >>= 1)
        acc += __shfl_down(acc, off, 16);

    if (sub == 0) {
        float o = (acc + conv_b[e]) * fc1_w[e] + fc1_b[0];
        out[s] = fmaxf(o, 0.0f);               // lanes 0,16,32,48 -> 16B coalesced
    }
}

extern "C" void kernel_launch(void* const* d_in, const int* in_sizes, int n_in,
                              void* d_out, int out_size, void* d_ws, size_t ws_size,
                              hipStream_t stream) {
    const float* x      = (const float*)d_in[0];
    const int*   cat    = (const int*)d_in[1];
    const float* conv_w = (const float*)d_in[2];
    const float* conv_b = (const float*)d_in[3];
    const float* fc1_w  = (const float*)d_in[4];
    const float* fc1_b  = (const float*)d_in[5];
    float* out = (float*)d_out;

    const int B = in_sizes[1];          // category_indices element count
    (void)d_ws; (void)ws_size; (void)n_in; (void)out_size;

    const int block = 256;              // 4 waves/block, 16 samples/block
    const int grid  = (B + 15) / 16;    // B=32768 -> 2048 blocks (8/CU)

    moe_conv_fused_kernel<<<grid, block, 0, stream>>>(
        x, cat, conv_w, conv_b, fc1_w, fc1_b, out, B);
}

// Round 4
// 20.686 us; speedup vs baseline: 1.3247x; 1.0115x over previous
//
#include <hip/hip_runtime.h>

#define KK 784      // 28*28 pixels per image
#define NE 5        // experts

__device__ __forceinline__ float dot4(float4 a, float4 b) {
    return a.x * b.x + a.y * b.y + a.z * b.z + a.w * b.w;
}

// One wave = 2 adjacent samples, one 32-lane group per sample, single pass.
// Low VGPR (xa[6] = 24 regs) so __launch_bounds__(256,8) -> 32 waves/CU,
// 2x the TLP of the previous 16-lane version. No LDS; weights (15.7 KB)
// are L1-resident after first touch.
__global__ __launch_bounds__(256, 8) void moe_conv_fused_kernel(
    const float* __restrict__ x,        // [B, 784]
    const int*   __restrict__ cat,      // [B]
    const float* __restrict__ conv_w,   // [5, 784]
    const float* __restrict__ conv_b,   // [5]
    const float* __restrict__ fc1_w,    // [1, 5] -> 5 floats
    const float* __restrict__ fc1_b,    // [1]
    float*       __restrict__ out,      // [B]
    int B)
{
    const int tid  = blockIdx.x * blockDim.x + threadIdx.x;
    const int wid  = tid >> 6;                 // global wave id
    const int lane = threadIdx.x & 63;
    const int grp  = lane >> 5;                // 0..1 : sample within wave
    const int sub  = lane & 31;                // lane within 32-lane group
    const int s    = wid * 2 + grp;            // sample id (one shot, no loop)
    if (s >= B) return;

    const int e = cat[s];                      // uniform per 32-lane group
    const float4* __restrict__ xv =
        reinterpret_cast<const float4*>(x) + (size_t)s * (KK / 4);
    const float4* __restrict__ wv =
        reinterpret_cast<const float4*>(conv_w) + (size_t)e * (KK / 4);

    // 196 float4 per sample over 32 lanes: 6 each + lanes 0..3 take #192+sub
    float4 xa[6];
    #pragma unroll
    for (int i = 0; i < 6; ++i)
        xa[i] = xv[sub + 32 * i];              // independent, issue back-to-back

    const bool extra = (sub < 4);
    float4 xt;
    if (extra) xt = xv[192 + sub];

    // weights stream from L1; 3 accumulators break the FMA chain
    float a0, a1, a2;
    {
        float4 w0 = wv[sub];
        float4 w1 = wv[sub + 32];
        float4 w2 = wv[sub + 64];
        a0 = dot4(xa[0], w0);
        a1 = dot4(xa[1], w1);
        a2 = dot4(xa[2], w2);
    }
    {
        float4 w0 = wv[sub + 96];
        float4 w1 = wv[sub + 128];
        float4 w2 = wv[sub + 160];
        a0 += dot4(xa[3], w0);
        a1 += dot4(xa[4], w1);
        a2 += dot4(xa[5], w2);
    }
    if (extra) {
        float4 wt = wv[192 + sub];
        a0 += dot4(xt, wt);
    }
    float acc = a0 + a1 + a2;

    // reduce within each 32-lane group (2 samples reduced simultaneously)
    #pragma unroll
    for (int off = 16; off > 0; off >>= 1)
        acc += __shfl_down(acc, off, 32);

    if (sub == 0) {
        float o = (acc + conv_b[e]) * fc1_w[e] + fc1_b[0];
        out[s] = fmaxf(o, 0.0f);               // lanes 0,32 -> adjacent floats
    }
}

extern "C" void kernel_launch(void* const* d_in, const int* in_sizes, int n_in,
                              void* d_out, int out_size, void* d_ws, size_t ws_size,
                              hipStream_t stream) {
    const float* x      = (const float*)d_in[0];
    const int*   cat    = (const int*)d_in[1];
    const float* conv_w = (const float*)d_in[2];
    const float* conv_b = (const float*)d_in[3];
    const float* fc1_w  = (const float*)d_in[4];
    const float* fc1_b  = (const float*)d_in[5];
    float* out = (float*)d_out;

    const int B = in_sizes[1];          // category_indices element count
    (void)d_ws; (void)ws_size; (void)n_in; (void)out_size;

    const int block = 256;              // 4 waves/block, 8 samples/block
    const int grid  = (B + 7) / 8;      // B=32768 -> 4096 blocks

    moe_conv_fused_kernel<<<grid, block, 0, stream>>>(
        x, cat, conv_w, conv_b, fc1_w, fc1_b, out, B);
}